// Round 14
// baseline (141.333 us; speedup 1.0000x reference)
//
#include <hip/hip_runtime.h>
#include <hip/hip_bf16.h>

#define N_NODES 256
#define BATCH   1024
#define ROWS    32    // batch rows per block (halved from 64: 2x blocks/CU,
                      // finer barrier granularity -> cross-block phase mixing)
#define ROWB    528   // padded LDS row stride (bytes), imm-offset addressing

typedef __attribute__((ext_vector_type(8))) short bf16x8;
typedef __attribute__((ext_vector_type(4))) float f32x4;

__device__ __forceinline__ float ftanh(float x) {
    float e = __builtin_amdgcn_exp2f(x * 2.8853900817779268f);
    float r = __builtin_amdgcn_rcpf(e + 1.0f);
    return fmaf(-2.0f, r, 1.0f);
}

__device__ __forceinline__ unsigned short f2bf(float f) {
    unsigned u = __float_as_uint(f);
    return (unsigned short)((u + 0x7fffu + ((u >> 16) & 1u)) >> 16);
}

__device__ __forceinline__ unsigned pack_bf2(float a, float b) {
    union { __hip_bfloat162 h; unsigned u; } cvt;
    cvt.h = __float22bfloat162_rn(make_float2(a, b));
    return cvt.u;
}

// DPP row_shr reduce; 16-lane sum lands in lane 15 (round-6 post-mortem).
template <int CTRL>
__device__ __forceinline__ float dpp_add(float s) {
    int t = __builtin_amdgcn_update_dpp(0, __float_as_int(s), CTRL, 0xf, 0xf, true);
    return s + __int_as_float(t);
}

// ---------------- P1: Z0 = x @ W0^T (fp32) + prep ----------------
__global__ void z0_prep(const float* __restrict__ x, const float* __restrict__ W0,
                        const float* __restrict__ W1, float* __restrict__ Z0,
                        float* __restrict__ xT, float* __restrict__ W0col,
                        unsigned short* __restrict__ W1bf) {
    __shared__ float xs[32][36];
    __shared__ float ws[32][36];
    int t = threadIdx.x;

    int gb = (blockIdx.y * 32 + blockIdx.x) * 256 + t;
    {
        int i = gb >> 8, m = gb & 255;
        W0col[gb] = W0[m * 256 + i];
        W1bf[gb]  = f2bf(W1[gb]);
    }
#pragma unroll
    for (int r = 0; r < 4; ++r) {
        int id = r * 65536 + gb;
        int i = id >> 10, b = id & 1023;
        xT[id] = x[b * 256 + i];
    }

    int b0 = blockIdx.x * 32, m0 = blockIdx.y * 32;
    int lr = t >> 3, lc = (t & 7) << 2;
    int tr = (t >> 4) << 1, tc = (t & 15) << 1;
    float acc00 = 0.f, acc01 = 0.f, acc10 = 0.f, acc11 = 0.f;
    for (int k0 = 0; k0 < 256; k0 += 32) {
        *(float4*)&xs[lr][lc] = *(const float4*)&x[(b0 + lr) * 256 + k0 + lc];
        *(float4*)&ws[lr][lc] = *(const float4*)&W0[(m0 + lr) * 256 + k0 + lc];
        __syncthreads();
#pragma unroll
        for (int k = 0; k < 32; ++k) {
            float a0 = xs[tr][k], a1 = xs[tr + 1][k];
            float w0v = ws[tc][k], w1v = ws[tc + 1][k];
            acc00 = fmaf(a0, w0v, acc00);
            acc01 = fmaf(a0, w1v, acc01);
            acc10 = fmaf(a1, w0v, acc10);
            acc11 = fmaf(a1, w1v, acc11);
        }
        __syncthreads();
    }
    Z0[(b0 + tr) * 256 + m0 + tc]         = acc00;
    Z0[(b0 + tr) * 256 + m0 + tc + 1]     = acc01;
    Z0[(b0 + tr + 1) * 256 + m0 + tc]     = acc10;
    Z0[(b0 + tr + 1) * 256 + m0 + tc + 1] = acc11;
}

// ---------------- F: fused per-(node i, 32-row batch tile) ----------------
// 4 waves x 256 threads, acc[2][4] (32 f32). LDS 17408 B -> up to 8 blocks/CU:
// 8 independent barrier-groups per CU stagger their VALU/MFMA/LDS phases.
// setprio(1) around the MFMA loop (T5; independent blocks = role diversity).
__launch_bounds__(256, 6)
__global__ void fused(const float* __restrict__ Z0, const float* __restrict__ xT,
                      const float* __restrict__ W0col,
                      const unsigned short* __restrict__ W1bf,
                      const float* __restrict__ W2, float* __restrict__ out) {
    __shared__ __align__(16) unsigned char h0s[ROWS * ROWB];  // 16.5 KiB
    __shared__ float wavepart[4 * ROWS];                       // 512 B
    const int t  = threadIdx.x;
    const int r0 = blockIdx.x * ROWS;  // batch tile base
    const int i  = blockIdx.y;         // node index

    const int wave = t >> 6, lane = t & 63;
    const int lr = lane & 15, lh = lane >> 4;

    // W2 values for this lane's 4 output columns (hide under phase 0)
    float w2v[4];
#pragma unroll
    for (int nt = 0; nt < 4; ++nt)
        w2v[nt] = W2[i * 256 + wave * 64 + nt * 16 + lr];

    // ---- phase 0: h0 = tanh(Z0 - x[:,i] (x) W0[:,i]) -> LDS (bf16, padded)
    {
        const int rowgrp = t >> 5, chunk = t & 31;   // 4 rows per thread
        const int col0 = chunk << 3;
        unsigned char* wbase = h0s + rowgrp * ROWB + chunk * 16;
        float4 w0a = *(const float4*)&W0col[i * 256 + col0];
        float4 w0b = *(const float4*)&W0col[i * 256 + col0 + 4];
        float w[8] = {w0a.x, w0a.y, w0a.z, w0a.w, w0b.x, w0b.y, w0b.z, w0b.w};
#pragma unroll
        for (int p = 0; p < 4; ++p) {
            int row = p * 8 + rowgrp;
            float xi = xT[i * 1024 + r0 + row];
            float4 za = *(const float4*)&Z0[(r0 + row) * 256 + col0];
            float4 zb = *(const float4*)&Z0[(r0 + row) * 256 + col0 + 4];
            float z[8] = {za.x, za.y, za.z, za.w, zb.x, zb.y, zb.z, zb.w};
            unsigned pk[4];
#pragma unroll
            for (int e = 0; e < 4; ++e) {
                float ha = ftanh(fmaf(-xi, w[2 * e],     z[2 * e]));
                float hb = ftanh(fmaf(-xi, w[2 * e + 1], z[2 * e + 1]));
                pk[e] = pack_bf2(ha, hb);
            }
            *(uint4*)(wbase + p * 8 * ROWB) = make_uint4(pk[0], pk[1], pk[2], pk[3]);
        }
    }
    __syncthreads();

    // ---- phase 1: z1 = h0 @ W1^T via MFMA (each wave: 32 rows x 64 cols)
    f32x4 acc[2][4];
#pragma unroll
    for (int a = 0; a < 2; ++a)
#pragma unroll
        for (int b = 0; b < 4; ++b)
            acc[a][b] = (f32x4){0.f, 0.f, 0.f, 0.f};

    const unsigned char* abase[2];
#pragma unroll
    for (int mt = 0; mt < 2; ++mt)
        abase[mt] = h0s + (mt * 16 + lr) * ROWB + lh * 16;

    const unsigned short* w1p[4];
#pragma unroll
    for (int nt = 0; nt < 4; ++nt)
        w1p[nt] = W1bf + (wave * 64 + nt * 16 + lr) * 256 + lh * 8;
    bf16x8 bnext[4];
#pragma unroll
    for (int nt = 0; nt < 4; ++nt)
        bnext[nt] = *(const bf16x8*)(w1p[nt]);

    __builtin_amdgcn_s_setprio(1);
#pragma unroll
    for (int ks = 0; ks < 8; ++ks) {
        bf16x8 bfrag[4];
#pragma unroll
        for (int nt = 0; nt < 4; ++nt) {
            bfrag[nt] = bnext[nt];
            if (ks < 7)
                bnext[nt] = *(const bf16x8*)(w1p[nt] + (ks + 1) * 32);
        }
        bf16x8 afrag[2];
#pragma unroll
        for (int mt = 0; mt < 2; ++mt)
            afrag[mt] = *(const bf16x8*)(abase[mt] + ks * 64);  // imm offset
#pragma unroll
        for (int mt = 0; mt < 2; ++mt)
#pragma unroll
            for (int nt = 0; nt < 4; ++nt)
                acc[mt][nt] = __builtin_amdgcn_mfma_f32_16x16x32_bf16(
                    afrag[mt], bfrag[nt], acc[mt][nt], 0, 0, 0);
    }
    __builtin_amdgcn_s_setprio(0);

    // ---- phase 2: h1 = tanh(z1); dot with W2 row i; DPP reduce (lane 15)
    //      C/D: row = mt*16 + lh*4 + r, col = wave*64 + nt*16 + lr
#pragma unroll
    for (int mt = 0; mt < 2; ++mt) {
#pragma unroll
        for (int r = 0; r < 4; ++r) {
            float s = fmaf(ftanh(acc[mt][0][r]), w2v[0],
                           ftanh(acc[mt][1][r]) * w2v[1]);
            s = fmaf(ftanh(acc[mt][2][r]), w2v[2], s);
            s = fmaf(ftanh(acc[mt][3][r]), w2v[3], s);
            s = dpp_add<0x118>(s);
            s = dpp_add<0x114>(s);
            s = dpp_add<0x112>(s);
            s = dpp_add<0x111>(s);   // sum at lane lr==15
            if (lr == 15)
                wavepart[wave * ROWS + mt * 16 + lh * 4 + r] = s;
        }
    }
    __syncthreads();

    // ---- phase 3: sum 4 wave partials, final tanh, store column i
    if (t < ROWS) {
        float s = wavepart[t] + wavepart[ROWS + t] +
                  wavepart[2 * ROWS + t] + wavepart[3 * ROWS + t];
        out[(r0 + t) * 256 + i] = ftanh(s);
    }
}

extern "C" void kernel_launch(void* const* d_in, const int* in_sizes, int n_in,
                              void* d_out, int out_size, void* d_ws, size_t ws_size,
                              hipStream_t stream) {
    const float* x  = (const float*)d_in[0];
    const float* W0 = (const float*)d_in[1];
    const float* W1 = (const float*)d_in[2];
    const float* W2 = (const float*)d_in[3];
    float* out = (float*)d_out;

    char* ws = (char*)d_ws;
    float* Z0            = (float*)ws;                               // 1 MB
    float* xT            = (float*)(ws + (1 << 20));                 // 1 MB
    float* W0col         = (float*)(ws + (2 << 20));                 // 256 KB
    unsigned short* W1bf = (unsigned short*)(ws + (2 << 20) + (256 << 10)); // 128 KB

    z0_prep<<<dim3(32, 8), 256, 0, stream>>>(x, W0, W1, Z0, xT, W0col, W1bf);
    fused<<<dim3(BATCH / ROWS, 256), 256, 0, stream>>>(Z0, xT, W0col, W1bf, W2, out);
}

// Round 15
// 92.980 us; speedup vs baseline: 1.5200x; 1.5200x over previous
//
#include <hip/hip_runtime.h>
#include <hip/hip_bf16.h>

#define N_NODES 256
#define BATCH   1024
#define ROWB    528   // padded LDS row stride (bytes), imm-offset addressing

typedef __attribute__((ext_vector_type(8))) short bf16x8;
typedef __attribute__((ext_vector_type(4))) float f32x4;

__device__ __forceinline__ float ftanh(float x) {
    // exact-ish tanh for prep/final (2 trans ops, used on only ~0.5M elems)
    float e = __builtin_amdgcn_exp2f(x * 2.8853900817779268f);
    float r = __builtin_amdgcn_rcpf(e + 1.0f);
    return fmaf(-2.0f, r, 1.0f);
}

// tanh(z - dl) given T = tanh(z): D = Pade[3/2](dl) (|dl|<=1.3, err<=1.1e-3),
// then (T-D)/(1-T*D) with both divisions fused into ONE rcp:
// (T*d - n)/(d - T*n), n/d = D. Exact at T = +-1. 8 VALU + 1 trans.
__device__ __forceinline__ float tanh_shift(float T, float dl) {
    float u = dl * dl;
    float n = dl * (u + 15.0f);
    float d = fmaf(6.0f, u, 15.0f);
    float num = fmaf(T, d, -n);
    float den = fmaf(-T, n, d);
    return num * __builtin_amdgcn_rcpf(den);
}

// tanh via Pade[5/4] + clamp: x(945+105u+u^2)/(945+420u+15u^2), u=x^2.
// err <= ~1.4e-3 (worst near |x|~3.7); ratio >= 1 for |x|>3.8 -> med3 clamp.
// 9 VALU + 1 trans (vs 4 + 2 for exp-form).
__device__ __forceinline__ float tanh_pade(float x) {
    float u = x * x;
    float n = x * fmaf(u + 105.0f, u, 945.0f);
    float d = fmaf(fmaf(15.0f, u, 420.0f), u, 945.0f);
    float r = n * __builtin_amdgcn_rcpf(d);
    return __builtin_amdgcn_fmed3f(r, -1.0f, 1.0f);
}

__device__ __forceinline__ unsigned short f2bf(float f) {
    unsigned u = __float_as_uint(f);
    return (unsigned short)((u + 0x7fffu + ((u >> 16) & 1u)) >> 16);
}

__device__ __forceinline__ unsigned pack_bf2(float a, float b) {
    union { __hip_bfloat162 h; unsigned u; } cvt;
    cvt.h = __float22bfloat162_rn(make_float2(a, b));
    return cvt.u;
}

// DPP row_shr reduce; 16-lane sum lands in lane 15 (round-6 post-mortem).
template <int CTRL>
__device__ __forceinline__ float dpp_add(float s) {
    int t = __builtin_amdgcn_update_dpp(0, __float_as_int(s), CTRL, 0xf, 0xf, true);
    return s + __int_as_float(t);
}

// ---------------- P1: T0 = tanh(x @ W0^T) (fp32) + prep ----------------
__global__ void z0_prep(const float* __restrict__ x, const float* __restrict__ W0,
                        const float* __restrict__ W1, float* __restrict__ T0,
                        float* __restrict__ xT, float* __restrict__ W0col,
                        unsigned short* __restrict__ W1bf) {
    __shared__ float xs[32][36];
    __shared__ float ws[32][36];
    int t = threadIdx.x;

    int gb = (blockIdx.y * 32 + blockIdx.x) * 256 + t;
    {
        int i = gb >> 8, m = gb & 255;
        W0col[gb] = W0[m * 256 + i];
        W1bf[gb]  = f2bf(W1[gb]);
    }
#pragma unroll
    for (int r = 0; r < 4; ++r) {
        int id = r * 65536 + gb;
        int i = id >> 10, b = id & 1023;
        xT[id] = x[b * 256 + i];
    }

    int b0 = blockIdx.x * 32, m0 = blockIdx.y * 32;
    int lr = t >> 3, lc = (t & 7) << 2;
    int tr = (t >> 4) << 1, tc = (t & 15) << 1;
    float acc00 = 0.f, acc01 = 0.f, acc10 = 0.f, acc11 = 0.f;
    for (int k0 = 0; k0 < 256; k0 += 32) {
        *(float4*)&xs[lr][lc] = *(const float4*)&x[(b0 + lr) * 256 + k0 + lc];
        *(float4*)&ws[lr][lc] = *(const float4*)&W0[(m0 + lr) * 256 + k0 + lc];
        __syncthreads();
#pragma unroll
        for (int k = 0; k < 32; ++k) {
            float a0 = xs[tr][k], a1 = xs[tr + 1][k];
            float w0v = ws[tc][k], w1v = ws[tc + 1][k];
            acc00 = fmaf(a0, w0v, acc00);
            acc01 = fmaf(a0, w1v, acc01);
            acc10 = fmaf(a1, w0v, acc10);
            acc11 = fmaf(a1, w1v, acc11);
        }
        __syncthreads();
    }
    // store tanh(z0): phase-0 uses the addition identity, so the raw z0
    // is never needed again.
    T0[(b0 + tr) * 256 + m0 + tc]         = ftanh(acc00);
    T0[(b0 + tr) * 256 + m0 + tc + 1]     = ftanh(acc01);
    T0[(b0 + tr + 1) * 256 + m0 + tc]     = ftanh(acc10);
    T0[(b0 + tr + 1) * 256 + m0 + tc + 1] = ftanh(acc11);
}

// ---------------- F: fused per-(node i, batch-tile) kernel ----------------
// R12 frame (best measured, 83.8 us) with the tanh math swapped to 1-trans
// forms: phase-0 via tanh-addition identity on precomputed T0, phase-2 via
// Pade[5/4]+clamp. Trans-unit lane-ops halve (268M -> 134M).
__launch_bounds__(256, 4)
__global__ void fused(const float* __restrict__ T0, const float* __restrict__ xT,
                      const float* __restrict__ W0col,
                      const unsigned short* __restrict__ W1bf,
                      const float* __restrict__ W2, float* __restrict__ out) {
    __shared__ __align__(16) unsigned char h0s[64 * ROWB];  // 33 KiB padded
    __shared__ float wavepart[4 * 64];                       // 1 KiB
    const int t  = threadIdx.x;
    const int r0 = blockIdx.x * 64;   // batch tile base
    const int i  = blockIdx.y;        // node index

    const int wave = t >> 6, lane = t & 63;
    const int lr = lane & 15, lh = lane >> 4;

    // W2 values for this lane's 4 output columns (hide latency under phase 0)
    float w2v[4];
#pragma unroll
    for (int nt = 0; nt < 4; ++nt)
        w2v[nt] = W2[i * 256 + wave * 64 + nt * 16 + lr];

    // ---- phase 0: h0 = tanh(z0 - xi*w0col) = (T - D)/(1 - T*D) -> LDS bf16
    {
        const int rowgrp = t >> 5, chunk = t & 31;   // 8 rows per thread
        const int col0 = chunk << 3;
        unsigned char* wbase = h0s + rowgrp * ROWB + chunk * 16;
        float4 w0a = *(const float4*)&W0col[i * 256 + col0];
        float4 w0b = *(const float4*)&W0col[i * 256 + col0 + 4];
        float w[8] = {w0a.x, w0a.y, w0a.z, w0a.w, w0b.x, w0b.y, w0b.z, w0b.w};
#pragma unroll
        for (int p = 0; p < 8; ++p) {
            int row = p * 8 + rowgrp;
            float xi = xT[i * 1024 + r0 + row];
            float4 ta = *(const float4*)&T0[(r0 + row) * 256 + col0];
            float4 tb = *(const float4*)&T0[(r0 + row) * 256 + col0 + 4];
            float tv[8] = {ta.x, ta.y, ta.z, ta.w, tb.x, tb.y, tb.z, tb.w};
            unsigned pk[4];
#pragma unroll
            for (int e = 0; e < 4; ++e) {
                float ha = tanh_shift(tv[2 * e],     xi * w[2 * e]);
                float hb = tanh_shift(tv[2 * e + 1], xi * w[2 * e + 1]);
                pk[e] = pack_bf2(ha, hb);
            }
            *(uint4*)(wbase + p * 8 * ROWB) = make_uint4(pk[0], pk[1], pk[2], pk[3]);
        }
    }
    __syncthreads();

    // ---- phase 1: z1 = h0 @ W1^T via MFMA (each wave: 64 rows x 64 cols)
    f32x4 acc[4][4];
#pragma unroll
    for (int a = 0; a < 4; ++a)
#pragma unroll
        for (int b = 0; b < 4; ++b)
            acc[a][b] = (f32x4){0.f, 0.f, 0.f, 0.f};

    const unsigned char* abase[4];
#pragma unroll
    for (int mt = 0; mt < 4; ++mt)
        abase[mt] = h0s + (mt * 16 + lr) * ROWB + lh * 16;

    const unsigned short* w1p[4];
#pragma unroll
    for (int nt = 0; nt < 4; ++nt)
        w1p[nt] = W1bf + (wave * 64 + nt * 16 + lr) * 256 + lh * 8;
    bf16x8 bnext[4];
#pragma unroll
    for (int nt = 0; nt < 4; ++nt)
        bnext[nt] = *(const bf16x8*)(w1p[nt]);

#pragma unroll
    for (int ks = 0; ks < 8; ++ks) {
        bf16x8 bfrag[4];
#pragma unroll
        for (int nt = 0; nt < 4; ++nt) {
            bfrag[nt] = bnext[nt];
            if (ks < 7)
                bnext[nt] = *(const bf16x8*)(w1p[nt] + (ks + 1) * 32);
        }
        bf16x8 afrag[4];
#pragma unroll
        for (int mt = 0; mt < 4; ++mt)
            afrag[mt] = *(const bf16x8*)(abase[mt] + ks * 64);  // imm offset
#pragma unroll
        for (int mt = 0; mt < 4; ++mt)
#pragma unroll
            for (int nt = 0; nt < 4; ++nt)
                acc[mt][nt] = __builtin_amdgcn_mfma_f32_16x16x32_bf16(
                    afrag[mt], bfrag[nt], acc[mt][nt], 0, 0, 0);
    }

    // ---- phase 2: h1 = tanh_pade(z1); dot with W2 row i; DPP reduce (lane 15)
    //      C/D: row = mt*16 + lh*4 + r, col = wave*64 + nt*16 + lr
#pragma unroll
    for (int mt = 0; mt < 4; ++mt) {
#pragma unroll
        for (int r = 0; r < 4; ++r) {
            float s = fmaf(tanh_pade(acc[mt][0][r]), w2v[0],
                           tanh_pade(acc[mt][1][r]) * w2v[1]);
            s = fmaf(tanh_pade(acc[mt][2][r]), w2v[2], s);
            s = fmaf(tanh_pade(acc[mt][3][r]), w2v[3], s);
            s = dpp_add<0x118>(s);   // row_shr:8
            s = dpp_add<0x114>(s);   // row_shr:4
            s = dpp_add<0x112>(s);   // row_shr:2
            s = dpp_add<0x111>(s);   // row_shr:1  -> lane 15 has the sum
            if (lr == 15)
                wavepart[wave * 64 + mt * 16 + lh * 4 + r] = s;
        }
    }
    __syncthreads();

    // ---- phase 3: sum 4 wave partials, final tanh (exact form), store col i
    if (t < 64) {
        float s = wavepart[t] + wavepart[64 + t] + wavepart[128 + t] + wavepart[192 + t];
        out[(r0 + t) * 256 + i] = ftanh(s);
    }
}

extern "C" void kernel_launch(void* const* d_in, const int* in_sizes, int n_in,
                              void* d_out, int out_size, void* d_ws, size_t ws_size,
                              hipStream_t stream) {
    const float* x  = (const float*)d_in[0];
    const float* W0 = (const float*)d_in[1];
    const float* W1 = (const float*)d_in[2];
    const float* W2 = (const float*)d_in[3];
    float* out = (float*)d_out;

    char* ws = (char*)d_ws;
    float* T0            = (float*)ws;                               // 1 MB
    float* xT            = (float*)(ws + (1 << 20));                 // 1 MB
    float* W0col         = (float*)(ws + (2 << 20));                 // 256 KB
    unsigned short* W1bf = (unsigned short*)(ws + (2 << 20) + (256 << 10)); // 128 KB

    z0_prep<<<dim3(32, 8), 256, 0, stream>>>(x, W0, W1, T0, xT, W0col, W1bf);
    fused<<<dim3(16, 256), 256, 0, stream>>>(T0, xT, W0col, W1bf, W2, out);
}

// Round 16
// 87.775 us; speedup vs baseline: 1.6102x; 1.0593x over previous
//
#include <hip/hip_runtime.h>
#include <hip/hip_bf16.h>

#define N_NODES 256
#define BATCH   1024
#define ROWB    528   // padded LDS row stride (bytes), imm-offset addressing
#define CSC     2.8853900817779268f   // 2*log2(e): tanh(x)=1-2/(exp2(c*x)+1)

typedef __attribute__((ext_vector_type(8))) short bf16x8;
typedef __attribute__((ext_vector_type(4))) float f32x4;
typedef __attribute__((ext_vector_type(2))) float f32x2;

__device__ __forceinline__ float ftanh(float x) {
    // full tanh for prep/final (input NOT prescaled)
    float e = __builtin_amdgcn_exp2f(x * CSC);
    float r = __builtin_amdgcn_rcpf(e + 1.0f);
    return fmaf(-2.0f, r, 1.0f);
}

__device__ __forceinline__ unsigned short f2bf(float f) {
    unsigned u = __float_as_uint(f);
    return (unsigned short)((u + 0x7fffu + ((u >> 16) & 1u)) >> 16);
}

__device__ __forceinline__ unsigned pack_bf2(float a, float b) {
    union { __hip_bfloat162 h; unsigned u; } cvt;
    cvt.h = __float22bfloat162_rn(make_float2(a, b));
    return cvt.u;
}

__device__ __forceinline__ f32x2 pkfma(f32x2 a, f32x2 b, f32x2 c) {
    return __builtin_elementwise_fma(a, b, c);   // -> v_pk_fma_f32
}

// tanh on a PRESCALED pair d2 = c*x: exp2 x2, pk_add, rcp x2, pk_fma.
__device__ __forceinline__ f32x2 tanh2_pre(f32x2 d2) {
    f32x2 e2;
    e2.x = __builtin_amdgcn_exp2f(d2.x);
    e2.y = __builtin_amdgcn_exp2f(d2.y);
    e2 = e2 + 1.0f;                               // v_pk_add_f32
    f32x2 r2;
    r2.x = __builtin_amdgcn_rcpf(e2.x);
    r2.y = __builtin_amdgcn_rcpf(e2.y);
    return pkfma((f32x2){-2.f, -2.f}, r2, (f32x2){1.f, 1.f});
}

// DPP row_shr reduce; 16-lane sum lands in lane 15 (round-6 post-mortem).
template <int CTRL>
__device__ __forceinline__ float dpp_add(float s) {
    int t = __builtin_amdgcn_update_dpp(0, __float_as_int(s), CTRL, 0xf, 0xf, true);
    return s + __int_as_float(t);
}

// ------- P1: Z0c = c*(x @ W0^T) + prep (all weights prescaled by c) -------
__global__ void z0_prep(const float* __restrict__ x, const float* __restrict__ W0,
                        const float* __restrict__ W1, float* __restrict__ Z0c,
                        float* __restrict__ xT, float* __restrict__ W0c,
                        unsigned short* __restrict__ W1bf) {
    __shared__ float xs[32][36];
    __shared__ float ws[32][36];
    int t = threadIdx.x;

    int gb = (blockIdx.y * 32 + blockIdx.x) * 256 + t;
    {
        int i = gb >> 8, m = gb & 255;
        W0c[gb]  = W0[m * 256 + i] * CSC;     // W0c[i*256+m] = c*W0[m][i]
        W1bf[gb] = f2bf(W1[gb] * CSC);        // c*W1 (bf16): MFMA yields c*z1
    }
#pragma unroll
    for (int r = 0; r < 4; ++r) {
        int id = r * 65536 + gb;
        int i = id >> 10, b = id & 1023;
        xT[id] = x[b * 256 + i];
    }

    int b0 = blockIdx.x * 32, m0 = blockIdx.y * 32;
    int lr = t >> 3, lc = (t & 7) << 2;
    int tr = (t >> 4) << 1, tc = (t & 15) << 1;
    float acc00 = 0.f, acc01 = 0.f, acc10 = 0.f, acc11 = 0.f;
    for (int k0 = 0; k0 < 256; k0 += 32) {
        *(float4*)&xs[lr][lc] = *(const float4*)&x[(b0 + lr) * 256 + k0 + lc];
        *(float4*)&ws[lr][lc] = *(const float4*)&W0[(m0 + lr) * 256 + k0 + lc];
        __syncthreads();
#pragma unroll
        for (int k = 0; k < 32; ++k) {
            float a0 = xs[tr][k], a1 = xs[tr + 1][k];
            float w0v = ws[tc][k], w1v = ws[tc + 1][k];
            acc00 = fmaf(a0, w0v, acc00);
            acc01 = fmaf(a0, w1v, acc01);
            acc10 = fmaf(a1, w0v, acc10);
            acc11 = fmaf(a1, w1v, acc11);
        }
        __syncthreads();
    }
    Z0c[(b0 + tr) * 256 + m0 + tc]         = acc00 * CSC;
    Z0c[(b0 + tr) * 256 + m0 + tc + 1]     = acc01 * CSC;
    Z0c[(b0 + tr + 1) * 256 + m0 + tc]     = acc10 * CSC;
    Z0c[(b0 + tr + 1) * 256 + m0 + tc + 1] = acc11 * CSC;
}

// ---------------- F: fused per-(node i, batch-tile) kernel ----------------
// R12 frame (best, 83.8us) + prescaled inputs + packed-f32 math: hot phases
// are VALU-issue bound (R15 inverse evidence), so minimize wave-instructions:
// phase0 ~4/elem (was 6), phase2 ~3.5/elem (was 7).
__launch_bounds__(256, 4)
__global__ void fused(const float* __restrict__ Z0c, const float* __restrict__ xT,
                      const float* __restrict__ W0c,
                      const unsigned short* __restrict__ W1bf,
                      const float* __restrict__ W2, float* __restrict__ out) {
    __shared__ __align__(16) unsigned char h0s[64 * ROWB];  // 33 KiB padded
    __shared__ float wavepart[4 * 64];                       // 1 KiB
    const int t  = threadIdx.x;
    const int r0 = blockIdx.x * 64;   // batch tile base
    const int i  = blockIdx.y;        // node index

    const int wave = t >> 6, lane = t & 63;
    const int lr = lane & 15, lh = lane >> 4;

    // W2 values for this lane's 4 output columns (hide latency under phase 0)
    float w2v[4];
#pragma unroll
    for (int nt = 0; nt < 4; ++nt)
        w2v[nt] = W2[i * 256 + wave * 64 + nt * 16 + lr];

    // ---- phase 0: h0 = tanh(z0 - xi*w0) via exp2 on prescaled operands
    {
        const int rowgrp = t >> 5, chunk = t & 31;   // 8 rows per thread
        const int col0 = chunk << 3;
        unsigned char* wbase = h0s + rowgrp * ROWB + chunk * 16;
        f32x2 wv[4];
        {
            float4 w0a = *(const float4*)&W0c[i * 256 + col0];
            float4 w0b = *(const float4*)&W0c[i * 256 + col0 + 4];
            wv[0] = (f32x2){w0a.x, w0a.y};
            wv[1] = (f32x2){w0a.z, w0a.w};
            wv[2] = (f32x2){w0b.x, w0b.y};
            wv[3] = (f32x2){w0b.z, w0b.w};
        }
#pragma unroll
        for (int p = 0; p < 8; ++p) {
            int row = p * 8 + rowgrp;
            float xi = xT[i * 1024 + r0 + row];
            f32x2 nxi = (f32x2){-xi, -xi};
            float4 za = *(const float4*)&Z0c[(r0 + row) * 256 + col0];
            float4 zb = *(const float4*)&Z0c[(r0 + row) * 256 + col0 + 4];
            f32x2 zv[4] = {(f32x2){za.x, za.y}, (f32x2){za.z, za.w},
                           (f32x2){zb.x, zb.y}, (f32x2){zb.z, zb.w}};
            unsigned pk[4];
#pragma unroll
            for (int e = 0; e < 4; ++e) {
                f32x2 h = tanh2_pre(pkfma(nxi, wv[e], zv[e]));  // (z-d)*c
                pk[e] = pack_bf2(h.x, h.y);
            }
            *(uint4*)(wbase + p * 8 * ROWB) = make_uint4(pk[0], pk[1], pk[2], pk[3]);
        }
    }
    __syncthreads();

    // ---- phase 1: c*z1 = h0 @ (c*W1)^T via MFMA (64 rows x 64 cols / wave)
    f32x4 acc[4][4];
#pragma unroll
    for (int a = 0; a < 4; ++a)
#pragma unroll
        for (int b = 0; b < 4; ++b)
            acc[a][b] = (f32x4){0.f, 0.f, 0.f, 0.f};

    const unsigned char* abase[4];
#pragma unroll
    for (int mt = 0; mt < 4; ++mt)
        abase[mt] = h0s + (mt * 16 + lr) * ROWB + lh * 16;

    const unsigned short* w1p[4];
#pragma unroll
    for (int nt = 0; nt < 4; ++nt)
        w1p[nt] = W1bf + (wave * 64 + nt * 16 + lr) * 256 + lh * 8;
    bf16x8 bnext[4];
#pragma unroll
    for (int nt = 0; nt < 4; ++nt)
        bnext[nt] = *(const bf16x8*)(w1p[nt]);

#pragma unroll
    for (int ks = 0; ks < 8; ++ks) {
        bf16x8 bfrag[4];
#pragma unroll
        for (int nt = 0; nt < 4; ++nt) {
            bfrag[nt] = bnext[nt];
            if (ks < 7)
                bnext[nt] = *(const bf16x8*)(w1p[nt] + (ks + 1) * 32);
        }
        bf16x8 afrag[4];
#pragma unroll
        for (int mt = 0; mt < 4; ++mt)
            afrag[mt] = *(const bf16x8*)(abase[mt] + ks * 64);  // imm offset
#pragma unroll
        for (int mt = 0; mt < 4; ++mt)
#pragma unroll
            for (int nt = 0; nt < 4; ++nt)
                acc[mt][nt] = __builtin_amdgcn_mfma_f32_16x16x32_bf16(
                    afrag[mt], bfrag[nt], acc[mt][nt], 0, 0, 0);
    }

    // ---- phase 2: h1 = tanh (exp2 directly on c-scaled acc); packed dot
    //      with W2; DPP reduce per output row (sum lands in lane 15).
    //      C/D: row = mt*16 + lh*4 + r, col = wave*64 + nt*16 + lr
#pragma unroll
    for (int mt = 0; mt < 4; ++mt) {
#pragma unroll
        for (int p = 0; p < 2; ++p) {          // r pairs (2p, 2p+1)
            f32x2 s2 = (f32x2){0.f, 0.f};
#pragma unroll
            for (int nt = 0; nt < 4; ++nt) {
                f32x2 zc = (f32x2){acc[mt][nt][2 * p], acc[mt][nt][2 * p + 1]};
                f32x2 h2 = tanh2_pre(zc);
                s2 = pkfma(h2, (f32x2){w2v[nt], w2v[nt]}, s2);
            }
#pragma unroll
            for (int q = 0; q < 2; ++q) {
                float s = s2[q];
                s = dpp_add<0x118>(s);   // row_shr:8
                s = dpp_add<0x114>(s);   // row_shr:4
                s = dpp_add<0x112>(s);   // row_shr:2
                s = dpp_add<0x111>(s);   // row_shr:1 -> lane 15 has the sum
                if (lr == 15)
                    wavepart[wave * 64 + mt * 16 + lh * 4 + 2 * p + q] = s;
            }
        }
    }
    __syncthreads();

    // ---- phase 3: sum 4 wave partials, final tanh (unscaled), store col i
    if (t < 64) {
        float s = wavepart[t] + wavepart[64 + t] + wavepart[128 + t] + wavepart[192 + t];
        out[(r0 + t) * 256 + i] = ftanh(s);
    }
}

extern "C" void kernel_launch(void* const* d_in, const int* in_sizes, int n_in,
                              void* d_out, int out_size, void* d_ws, size_t ws_size,
                              hipStream_t stream) {
    const float* x  = (const float*)d_in[0];
    const float* W0 = (const float*)d_in[1];
    const float* W1 = (const float*)d_in[2];
    const float* W2 = (const float*)d_in[3];
    float* out = (float*)d_out;

    char* ws = (char*)d_ws;
    float* Z0c           = (float*)ws;                               // 1 MB
    float* xT            = (float*)(ws + (1 << 20));                 // 1 MB
    float* W0c           = (float*)(ws + (2 << 20));                 // 256 KB
    unsigned short* W1bf = (unsigned short*)(ws + (2 << 20) + (256 << 10)); // 128 KB

    z0_prep<<<dim3(32, 8), 256, 0, stream>>>(x, W0, W1, Z0c, xT, W0c, W1bf);
    fused<<<dim3(16, 256), 256, 0, stream>>>(Z0c, xT, W0c, W1bf, W2, out);
}